// Round 1
// baseline (2157.014 us; speedup 1.0000x reference)
//
#include <hip/hip_runtime.h>

// KiloNeRF grouped tiny-MLP — round 6: lane-per-point, zero-LDS, barrier-free.
//
// Round-5 counters: VALUBusy 21%, HBM 4.3%, occupancy 21%, 3M LDS bank-conflict
// cycles -> latency-bound on the per-point LDS/shuffle dependency chain.
// Round-6 restructure: wave = (expert, 32-point chunk); lane = (point, out-half).
// Each lane computes 16 of 32 outputs for ITS point entirely in registers;
// weights are wave-uniform (per half) and read straight from global memory in
// the ORIGINAL [i][o] layout (broadcast 16B loads) -- no LDS, no __syncthreads.
// posenc is generated on the fly (sincosf + exact *2 doubling == 2.0**l * x),
// so xp[63] is never materialized. The only cross-lane traffic is a 16-value
// half-exchange (shfl_xor 32) after each layer.

// ---- workspace layout (ints) ----
#define WS_COUNTS 0
#define WS_OFFSETS 4096
#define WS_CURSOR 8192
#define WS_ORDER 12288

__device__ __forceinline__ int expert_id(float px, float py, float pz) {
    float nx = (px - (-1.5f)) / 3.0f;
    float ny = (py - (-1.5f)) / 3.0f;
    float nz = (pz - (-1.5f)) / 3.0f;
    float sx = fminf(fmaxf(nx * 16.0f, 0.0f), 15.0f);
    float sy = fminf(fmaxf(ny * 16.0f, 0.0f), 15.0f);
    float sz = fminf(fmaxf(nz * 16.0f, 0.0f), 15.0f);
    return (int)sx * 256 + (int)sy * 16 + (int)sz;
}

// acc[0..15] += x * row[0..15]   (row is 16B-aligned, uniform per half)
__device__ __forceinline__ void fma16(float acc[16], const float* __restrict__ row,
                                      float x) {
#pragma unroll
    for (int k = 0; k < 16; k += 4) {
        const float4 w = *(const float4*)(row + k);
        acc[k + 0] = fmaf(x, w.x, acc[k + 0]);
        acc[k + 1] = fmaf(x, w.y, acc[k + 1]);
        acc[k + 2] = fmaf(x, w.z, acc[k + 2]);
        acc[k + 3] = fmaf(x, w.w, acc[k + 3]);
    }
}

__device__ __forceinline__ void ld_bias16(float acc[16], const float* __restrict__ b) {
#pragma unroll
    for (int k = 0; k < 16; k += 4) {
        const float4 v = *(const float4*)(b + k);
        acc[k + 0] = v.x; acc[k + 1] = v.y; acc[k + 2] = v.z; acc[k + 3] = v.w;
    }
}

// halves hold h[ob..ob+15]; exchange so every lane ends with full h[0..31]
template <bool RELU>
__device__ __forceinline__ void exch32(float out[32], const float acc[16], int hi) {
#pragma unroll
    for (int k = 0; k < 16; ++k) {
        float own = RELU ? fmaxf(acc[k], 0.f) : acc[k];
        float oth = __shfl_xor(own, 32, 64);
        out[k]      = hi ? oth : own;
        out[k + 16] = hi ? own : oth;
    }
}

// ---------------- pass A: histogram ----------------
__global__ __launch_bounds__(256) void hist_kernel(const float* __restrict__ pts,
                                                   int* __restrict__ counts, int n) {
    int i = blockIdx.x * 256 + threadIdx.x;
    if (i < n) {
        int e = expert_id(pts[3 * i + 0], pts[3 * i + 1], pts[3 * i + 2]);
        atomicAdd(&counts[e], 1);
    }
}

// ---------------- pass B: exclusive scan of 4096 counts (1 block) ----------
__global__ __launch_bounds__(256) void scan_kernel(const int* __restrict__ counts,
                                                   int* __restrict__ offsets,
                                                   int* __restrict__ cursor) {
    const int tid = threadIdx.x;
    const int lane = tid & 63, wave = tid >> 6;
    const int base = tid * 16;
    int c[16], loc[16], sum = 0;
#pragma unroll
    for (int j = 0; j < 16; ++j) c[j] = counts[base + j];
#pragma unroll
    for (int j = 0; j < 16; ++j) { loc[j] = sum; sum += c[j]; }
    int v = sum;
#pragma unroll
    for (int off = 1; off <= 32; off <<= 1) {
        int u = __shfl_up(v, off, 64);
        if (lane >= off) v += u;
    }
    __shared__ int wtot[4];
    if (lane == 63) wtot[wave] = v;
    __syncthreads();
    int wbase = 0;
    for (int w = 0; w < wave; ++w) wbase += wtot[w];
    const int excl = wbase + v - sum;
#pragma unroll
    for (int j = 0; j < 16; ++j) {
        int o = excl + loc[j];
        offsets[base + j] = o;
        cursor[base + j] = o;
    }
}

// ---------------- pass C: scatter point ids into buckets ----------------
__global__ __launch_bounds__(256) void scatter_kernel(const float* __restrict__ pts,
                                                      int* __restrict__ cursor,
                                                      int* __restrict__ order, int n) {
    int i = blockIdx.x * 256 + threadIdx.x;
    if (i < n) {
        int e = expert_id(pts[3 * i + 0], pts[3 * i + 1], pts[3 * i + 2]);
        int pos = atomicAdd(&cursor[e], 1);
        order[pos] = i;
    }
}

// ---------------- pass D: wave per (expert, 32-pt chunk), lane = (pt, half) ----
__global__ __launch_bounds__(64) void expert_mlp_kernel(
    const float* __restrict__ pts, const float* __restrict__ viewdirs,
    const float* __restrict__ W1, const float* __restrict__ b1,
    const float* __restrict__ W2, const float* __restrict__ b2,
    const float* __restrict__ Wf, const float* __restrict__ bfc,
    const float* __restrict__ Wsig, const float* __restrict__ bsig,
    const float* __restrict__ Wv, const float* __restrict__ bv,
    const float* __restrict__ Wrgb, const float* __restrict__ brgb,
    const int* __restrict__ counts, const int* __restrict__ offsets,
    const int* __restrict__ order,
    float* __restrict__ out_rgb, float* __restrict__ out_sigma, int samples) {

    const int e = blockIdx.x >> 1;
    const int chunk = blockIdx.x & 1;
    const int cnt = counts[e];
    if (chunk * 32 >= cnt) return;
    const int start = offsets[e];

    const int lane = threadIdx.x;
    const int pidx = lane & 31;      // point slot within chunk
    const int hi = lane >> 5;        // output half
    const int ob = hi << 4;          // output base (0 or 16)

    // per-expert weight bases, half-offset folded in; all 16B-aligned
    const float* __restrict__ W1o = W1 + (size_t)e * 2016 + ob;   // [63][32]
    const float* __restrict__ W2o = W2 + (size_t)e * 1024 + ob;   // [32][32]
    const float* __restrict__ Wfo = Wf + (size_t)e * 1024 + ob;   // [32][32]
    const float* __restrict__ Wvo = Wv + (size_t)e * 1888 + ob;   // [59][32]
    const float* __restrict__ Wse = Wsig + (size_t)e * 32;        // [32]
    const float* __restrict__ Wre = Wrgb + (size_t)e * 96;        // [32][3] flat

    for (int s0 = chunk * 32; s0 < cnt; s0 += 64) {
        const int s = s0 + pidx;
        const bool live = (s < cnt);
        const bool act = live && (hi == 0);
        const int pt = order[start + (live ? s : (cnt - 1))];

        const float px = pts[3 * pt + 0];
        const float py = pts[3 * pt + 1];
        const float pz = pts[3 * pt + 2];
        const int ray = pt / samples;
        const float dx = viewdirs[3 * ray + 0];
        const float dy = viewdirs[3 * ray + 1];
        const float dz = viewdirs[3 * ray + 2];

        // ---- layer 1: 63 -> 32, posenc(p) generated on the fly ----
        float acc[16];
        ld_bias16(acc, b1 + e * 32 + ob);
        fma16(acc, W1o + 0 * 32, px);
        fma16(acc, W1o + 1 * 32, py);
        fma16(acc, W1o + 2 * 32, pz);
        {
            float tx = px, ty = py, tz = pz;   // exact *2 doubling == 2^l * x
            for (int l = 0; l < 10; ++l) {
                float sx, cx, sy, cy, sz, cz;
                sincosf(tx, &sx, &cx);
                sincosf(ty, &sy, &cy);
                sincosf(tz, &sz, &cz);
                const float* r = W1o + (3 + 6 * l) * 32;
                fma16(acc, r + 0 * 32, sx);
                fma16(acc, r + 1 * 32, sy);
                fma16(acc, r + 2 * 32, sz);
                fma16(acc, r + 3 * 32, cx);
                fma16(acc, r + 4 * 32, cy);
                fma16(acc, r + 5 * 32, cz);
                tx += tx; ty += ty; tz += tz;
            }
        }
        float h32[32];
        exch32<true>(h32, acc, hi);            // h1 (relu'd), full vector/lane

        // ---- layer 2: 32 -> 32 ----
        float acc2[16];
        ld_bias16(acc2, b2 + e * 32 + ob);
#pragma unroll
        for (int i = 0; i < 32; ++i) fma16(acc2, W2o + i * 32, h32[i]);
        float g32[32];
        exch32<true>(g32, acc2, hi);           // h2 (relu'd)

        // ---- sigma head: dot(h2, Wsig) + bsig (all lanes, half-0 stores) ----
        {
            float sg = bsig[e];
#pragma unroll
            for (int q = 0; q < 8; ++q) {
                const float4 w = *(const float4*)(Wse + 4 * q);
                sg = fmaf(g32[4 * q + 0], w.x, sg);
                sg = fmaf(g32[4 * q + 1], w.y, sg);
                sg = fmaf(g32[4 * q + 2], w.z, sg);
                sg = fmaf(g32[4 * q + 3], w.w, sg);
            }
            if (act) out_sigma[pt] = sg;
        }

        // ---- feat: 32 -> 32, no relu ----
        float accf[16];
        ld_bias16(accf, bfc + e * 32 + ob);
#pragma unroll
        for (int i = 0; i < 32; ++i) fma16(accf, Wfo + i * 32, g32[i]);
        float f32[32];
        exch32<false>(f32, accf, hi);          // feat

        // ---- view layer: 59 -> 32 (inputs = [feat, posenc(d)]) ----
        float accv[16];
        ld_bias16(accv, bv + e * 32 + ob);
#pragma unroll
        for (int i = 0; i < 32; ++i) fma16(accv, Wvo + i * 32, f32[i]);
        fma16(accv, Wvo + 32 * 32, dx);
        fma16(accv, Wvo + 33 * 32, dy);
        fma16(accv, Wvo + 34 * 32, dz);
        {
            float tx = dx, ty = dy, tz = dz;
            for (int l = 0; l < 4; ++l) {
                float sx, cx, sy, cy, sz, cz;
                sincosf(tx, &sx, &cx);
                sincosf(ty, &sy, &cy);
                sincosf(tz, &sz, &cz);
                const float* r = Wvo + (35 + 6 * l) * 32;
                fma16(accv, r + 0 * 32, sx);
                fma16(accv, r + 1 * 32, sy);
                fma16(accv, r + 2 * 32, sz);
                fma16(accv, r + 3 * 32, cx);
                fma16(accv, r + 4 * 32, cy);
                fma16(accv, r + 5 * 32, cz);
                tx += tx; ty += ty; tz += tz;
            }
        }
        float v32[32];
        exch32<true>(v32, accv, hi);           // hv (relu'd)

        // ---- rgb head: 3 dots over 32; Wrgb is [32][3] -> stream as float4 ----
        {
            float rgb[3];
            rgb[0] = brgb[3 * e + 0];
            rgb[1] = brgb[3 * e + 1];
            rgb[2] = brgb[3 * e + 2];
#pragma unroll
            for (int q = 0; q < 24; ++q) {
                const float4 w = *(const float4*)(Wre + 4 * q);
                const float wv[4] = {w.x, w.y, w.z, w.w};
#pragma unroll
                for (int j = 0; j < 4; ++j) {
                    const int idx = 4 * q + j;
                    const int i = idx / 3;
                    const int c = idx - 3 * i;
                    rgb[c] = fmaf(v32[i], wv[j], rgb[c]);
                }
            }
            if (act) {
                out_rgb[3 * pt + 0] = rgb[0];
                out_rgb[3 * pt + 1] = rgb[1];
                out_rgb[3 * pt + 2] = rgb[2];
            }
        }
    }
}

extern "C" void kernel_launch(void* const* d_in, const int* in_sizes, int n_in,
                              void* d_out, int out_size, void* d_ws, size_t ws_size,
                              hipStream_t stream) {
    const float* pts      = (const float*)d_in[0];
    const float* viewdirs = (const float*)d_in[1];
    const float* W1   = (const float*)d_in[2];
    const float* b1   = (const float*)d_in[3];
    const float* W2   = (const float*)d_in[4];
    const float* b2   = (const float*)d_in[5];
    const float* Wf   = (const float*)d_in[6];
    const float* bfc  = (const float*)d_in[7];
    const float* Wsig = (const float*)d_in[8];
    const float* bsig = (const float*)d_in[9];
    const float* Wv   = (const float*)d_in[10];
    const float* bv   = (const float*)d_in[11];
    const float* Wrgb = (const float*)d_in[12];
    const float* brgb = (const float*)d_in[13];

    const int n = in_sizes[0] / 3;          // 65536 points
    const int n_rays = in_sizes[1] / 3;     // 1024 rays
    const int samples = n / n_rays;         // 64 samples/ray

    float* out_rgb = (float*)d_out;
    float* out_sigma = out_rgb + (size_t)n * 3;

    int* ws = (int*)d_ws;
    int* counts = ws + WS_COUNTS;
    int* offsets = ws + WS_OFFSETS;
    int* cursor = ws + WS_CURSOR;
    int* order = ws + WS_ORDER;

    hipMemsetAsync(counts, 0, 4096 * sizeof(int), stream);
    hist_kernel<<<(n + 255) / 256, 256, 0, stream>>>(pts, counts, n);
    scan_kernel<<<1, 256, 0, stream>>>(counts, offsets, cursor);
    scatter_kernel<<<(n + 255) / 256, 256, 0, stream>>>(pts, cursor, order, n);
    expert_mlp_kernel<<<4096 * 2, 64, 0, stream>>>(
        pts, viewdirs, W1, b1, W2, b2, Wf, bfc, Wsig, bsig, Wv, bv, Wrgb, brgb,
        counts, offsets, order, out_rgb, out_sigma, samples);
}

// Round 2
// 500.818 us; speedup vs baseline: 4.3070x; 4.3070x over previous
//
#include <hip/hip_runtime.h>

// KiloNeRF grouped tiny-MLP — round 7: lane-per-point, spill-free.
//
// Round-6 post-mortem: VGPR=256 + 1.45GB WRITE_SIZE = register spill to
// scratch (full 32-float activation vectors per lane + fully-unrolled 32-iter
// matvec loops hoisting 128 float4 weight loads). VALUBusy 1.4%.
// Round-7: keep wave=(expert, 32-pt chunk), lane=(point, half). Each lane
// holds ONLY its half act[16]; the partner half's scalar is fetched on the fly
// with __shfl_xor(...,32) inside the matvec (16 shfl/layer). Unrolling bounded
// (unroll 2 on split-matvecs, unroll 1 on posenc level loops) so <=16 float4
// weight loads are in flight. Weights read straight from global in original
// [i][o] layout (half-uniform broadcast loads); no LDS, no __syncthreads.

// ---- workspace layout (ints) ----
#define WS_COUNTS 0
#define WS_OFFSETS 4096
#define WS_CURSOR 8192
#define WS_ORDER 12288

__device__ __forceinline__ int expert_id(float px, float py, float pz) {
    float nx = (px - (-1.5f)) / 3.0f;
    float ny = (py - (-1.5f)) / 3.0f;
    float nz = (pz - (-1.5f)) / 3.0f;
    float sx = fminf(fmaxf(nx * 16.0f, 0.0f), 15.0f);
    float sy = fminf(fmaxf(ny * 16.0f, 0.0f), 15.0f);
    float sz = fminf(fmaxf(nz * 16.0f, 0.0f), 15.0f);
    return (int)sx * 256 + (int)sy * 16 + (int)sz;
}

// acc[0..15] += x * row[0..15]   (row 16B-aligned, uniform per half)
__device__ __forceinline__ void fma16(float acc[16], const float* __restrict__ row,
                                      float x) {
#pragma unroll
    for (int k = 0; k < 16; k += 4) {
        const float4 w = *(const float4*)(row + k);
        acc[k + 0] = fmaf(x, w.x, acc[k + 0]);
        acc[k + 1] = fmaf(x, w.y, acc[k + 1]);
        acc[k + 2] = fmaf(x, w.z, acc[k + 2]);
        acc[k + 3] = fmaf(x, w.w, acc[k + 3]);
    }
}

__device__ __forceinline__ void ld_bias16(float acc[16], const float* __restrict__ b) {
#pragma unroll
    for (int k = 0; k < 16; k += 4) {
        const float4 v = *(const float4*)(b + k);
        acc[k + 0] = v.x; acc[k + 1] = v.y; acc[k + 2] = v.z; acc[k + 3] = v.w;
    }
}

// acc[ob..ob+15] += sum_{i=0..31} h[i] * W[i][ob..ob+15], where this lane holds
// act[ii] = h[ob+ii] and the partner lane (lane^32) holds h[(ob^16)+ii].
__device__ __forceinline__ void matvec_split(float acc[16], const float* __restrict__ Wexp,
                                             const float act[16], int ob) {
    const float* __restrict__ Wself = Wexp + (ob) * 32 + ob;
    const float* __restrict__ Woth  = Wexp + (ob ^ 16) * 32 + ob;
#pragma unroll 2
    for (int ii = 0; ii < 16; ++ii) {
        const float hs = act[ii];
        const float ho = __shfl_xor(hs, 32, 64);
        fma16(acc, Wself + ii * 32, hs);
        fma16(acc, Woth + ii * 32, ho);
    }
}

// ---------------- pass A: histogram ----------------
__global__ __launch_bounds__(256) void hist_kernel(const float* __restrict__ pts,
                                                   int* __restrict__ counts, int n) {
    int i = blockIdx.x * 256 + threadIdx.x;
    if (i < n) {
        int e = expert_id(pts[3 * i + 0], pts[3 * i + 1], pts[3 * i + 2]);
        atomicAdd(&counts[e], 1);
    }
}

// ---------------- pass B: exclusive scan of 4096 counts (1 block) ----------
__global__ __launch_bounds__(256) void scan_kernel(const int* __restrict__ counts,
                                                   int* __restrict__ offsets,
                                                   int* __restrict__ cursor) {
    const int tid = threadIdx.x;
    const int lane = tid & 63, wave = tid >> 6;
    const int base = tid * 16;
    int c[16], loc[16], sum = 0;
#pragma unroll
    for (int j = 0; j < 16; ++j) c[j] = counts[base + j];
#pragma unroll
    for (int j = 0; j < 16; ++j) { loc[j] = sum; sum += c[j]; }
    int v = sum;
#pragma unroll
    for (int off = 1; off <= 32; off <<= 1) {
        int u = __shfl_up(v, off, 64);
        if (lane >= off) v += u;
    }
    __shared__ int wtot[4];
    if (lane == 63) wtot[wave] = v;
    __syncthreads();
    int wbase = 0;
    for (int w = 0; w < wave; ++w) wbase += wtot[w];
    const int excl = wbase + v - sum;
#pragma unroll
    for (int j = 0; j < 16; ++j) {
        int o = excl + loc[j];
        offsets[base + j] = o;
        cursor[base + j] = o;
    }
}

// ---------------- pass C: scatter point ids into buckets ----------------
__global__ __launch_bounds__(256) void scatter_kernel(const float* __restrict__ pts,
                                                      int* __restrict__ cursor,
                                                      int* __restrict__ order, int n) {
    int i = blockIdx.x * 256 + threadIdx.x;
    if (i < n) {
        int e = expert_id(pts[3 * i + 0], pts[3 * i + 1], pts[3 * i + 2]);
        int pos = atomicAdd(&cursor[e], 1);
        order[pos] = i;
    }
}

// ---------------- pass D: wave per (expert, 32-pt chunk), lane = (pt, half) ----
__global__ __launch_bounds__(64, 2) void expert_mlp_kernel(
    const float* __restrict__ pts, const float* __restrict__ viewdirs,
    const float* __restrict__ W1, const float* __restrict__ b1,
    const float* __restrict__ W2, const float* __restrict__ b2,
    const float* __restrict__ Wf, const float* __restrict__ bfc,
    const float* __restrict__ Wsig, const float* __restrict__ bsig,
    const float* __restrict__ Wv, const float* __restrict__ bv,
    const float* __restrict__ Wrgb, const float* __restrict__ brgb,
    const int* __restrict__ counts, const int* __restrict__ offsets,
    const int* __restrict__ order,
    float* __restrict__ out_rgb, float* __restrict__ out_sigma, int samples) {

    const int e = blockIdx.x >> 1;
    const int chunk = blockIdx.x & 1;
    const int cnt = counts[e];
    if (chunk * 32 >= cnt) return;
    const int start = offsets[e];

    const int lane = threadIdx.x;
    const int pidx = lane & 31;      // point slot within chunk
    const int hi = lane >> 5;        // output half
    const int ob = hi << 4;          // output base (0 or 16)

    // samples is a power of two (64) -> shift; keep a uniform fallback
    const bool pow2 = (samples & (samples - 1)) == 0;
    const int sh = 31 - __clz(samples);

    const float* __restrict__ W1o = W1 + (size_t)e * 2016 + ob;   // [63][32]
    const float* __restrict__ W2e = W2 + (size_t)e * 1024;        // [32][32]
    const float* __restrict__ Wfe = Wf + (size_t)e * 1024;        // [32][32]
    const float* __restrict__ Wve = Wv + (size_t)e * 1888;        // [59][32]
    const float* __restrict__ Wvo = Wve + ob;
    const float* __restrict__ Wse = Wsig + (size_t)e * 32;        // [32]
    const float* __restrict__ Wre = Wrgb + (size_t)e * 96;        // [32][3]

    for (int s0 = chunk * 32; s0 < cnt; s0 += 64) {
        const int s = s0 + pidx;
        const bool live = (s < cnt);
        const bool act_store = live && (hi == 0);
        const int pt = order[start + (live ? s : (cnt - 1))];

        const float px = pts[3 * pt + 0];
        const float py = pts[3 * pt + 1];
        const float pz = pts[3 * pt + 2];
        const int ray = pow2 ? (pt >> sh) : (pt / samples);
        const float dx = viewdirs[3 * ray + 0];
        const float dy = viewdirs[3 * ray + 1];
        const float dz = viewdirs[3 * ray + 2];

        // ---- layer 1: 63 -> 32 (this half's 16), posenc(p) on the fly ----
        float acc[16];
        ld_bias16(acc, b1 + e * 32 + ob);
        fma16(acc, W1o + 0 * 32, px);
        fma16(acc, W1o + 1 * 32, py);
        fma16(acc, W1o + 2 * 32, pz);
        {
            float tx = px, ty = py, tz = pz;   // exact *2 doubling == 2^l * x
#pragma unroll 1
            for (int l = 0; l < 10; ++l) {
                float sx, cx, sy, cy, sz, cz;
                sincosf(tx, &sx, &cx);
                sincosf(ty, &sy, &cy);
                sincosf(tz, &sz, &cz);
                const float* r = W1o + (3 + 6 * l) * 32;
                fma16(acc, r + 0 * 32, sx);
                fma16(acc, r + 1 * 32, sy);
                fma16(acc, r + 2 * 32, sz);
                fma16(acc, r + 3 * 32, cx);
                fma16(acc, r + 4 * 32, cy);
                fma16(acc, r + 5 * 32, cz);
                tx += tx; ty += ty; tz += tz;
            }
        }
        float h[16];
#pragma unroll
        for (int k = 0; k < 16; ++k) h[k] = fmaxf(acc[k], 0.f);

        // ---- layer 2: 32 -> 32 ----
        float acc2[16];
        ld_bias16(acc2, b2 + e * 32 + ob);
        matvec_split(acc2, W2e, h, ob);
        float g[16];
#pragma unroll
        for (int k = 0; k < 16; ++k) g[k] = fmaxf(acc2[k], 0.f);

        // ---- sigma head: half-partial dot + one shfl-add ----
        {
            float sg = 0.f;
#pragma unroll
            for (int q = 0; q < 4; ++q) {
                const float4 w = *(const float4*)(Wse + ob + 4 * q);
                sg = fmaf(g[4 * q + 0], w.x, sg);
                sg = fmaf(g[4 * q + 1], w.y, sg);
                sg = fmaf(g[4 * q + 2], w.z, sg);
                sg = fmaf(g[4 * q + 3], w.w, sg);
            }
            sg += __shfl_xor(sg, 32, 64);
            if (act_store) out_sigma[pt] = sg + bsig[e];
        }

        // ---- feat: 32 -> 32, no relu ----
        float f[16];
        ld_bias16(f, bfc + e * 32 + ob);
        matvec_split(f, Wfe, g, ob);

        // ---- view layer: 59 -> 32 (inputs = [feat(32, split), posenc(d)]) ----
        float accv[16];
        ld_bias16(accv, bv + e * 32 + ob);
        matvec_split(accv, Wve, f, ob);
        fma16(accv, Wvo + 32 * 32, dx);
        fma16(accv, Wvo + 33 * 32, dy);
        fma16(accv, Wvo + 34 * 32, dz);
        {
            float tx = dx, ty = dy, tz = dz;
#pragma unroll 1
            for (int l = 0; l < 4; ++l) {
                float sx, cx, sy, cy, sz, cz;
                sincosf(tx, &sx, &cx);
                sincosf(ty, &sy, &cy);
                sincosf(tz, &sz, &cz);
                const float* r = Wvo + (35 + 6 * l) * 32;
                fma16(accv, r + 0 * 32, sx);
                fma16(accv, r + 1 * 32, sy);
                fma16(accv, r + 2 * 32, sz);
                fma16(accv, r + 3 * 32, cx);
                fma16(accv, r + 4 * 32, cy);
                fma16(accv, r + 5 * 32, cz);
                tx += tx; ty += ty; tz += tz;
            }
        }
        float v[16];
#pragma unroll
        for (int k = 0; k < 16; ++k) v[k] = fmaxf(accv[k], 0.f);

        // ---- rgb head: 3 half-partial dots + shfl-adds ----
        {
            float r0 = 0.f, r1 = 0.f, r2 = 0.f;
#pragma unroll 4
            for (int k = 0; k < 16; ++k) {
                const float* wr = Wre + (ob + k) * 3;
                r0 = fmaf(v[k], wr[0], r0);
                r1 = fmaf(v[k], wr[1], r1);
                r2 = fmaf(v[k], wr[2], r2);
            }
            r0 += __shfl_xor(r0, 32, 64);
            r1 += __shfl_xor(r1, 32, 64);
            r2 += __shfl_xor(r2, 32, 64);
            if (act_store) {
                out_rgb[3 * pt + 0] = r0 + brgb[3 * e + 0];
                out_rgb[3 * pt + 1] = r1 + brgb[3 * e + 1];
                out_rgb[3 * pt + 2] = r2 + brgb[3 * e + 2];
            }
        }
    }
}

extern "C" void kernel_launch(void* const* d_in, const int* in_sizes, int n_in,
                              void* d_out, int out_size, void* d_ws, size_t ws_size,
                              hipStream_t stream) {
    const float* pts      = (const float*)d_in[0];
    const float* viewdirs = (const float*)d_in[1];
    const float* W1   = (const float*)d_in[2];
    const float* b1   = (const float*)d_in[3];
    const float* W2   = (const float*)d_in[4];
    const float* b2   = (const float*)d_in[5];
    const float* Wf   = (const float*)d_in[6];
    const float* bfc  = (const float*)d_in[7];
    const float* Wsig = (const float*)d_in[8];
    const float* bsig = (const float*)d_in[9];
    const float* Wv   = (const float*)d_in[10];
    const float* bv   = (const float*)d_in[11];
    const float* Wrgb = (const float*)d_in[12];
    const float* brgb = (const float*)d_in[13];

    const int n = in_sizes[0] / 3;          // 65536 points
    const int n_rays = in_sizes[1] / 3;     // 1024 rays
    const int samples = n / n_rays;         // 64 samples/ray

    float* out_rgb = (float*)d_out;
    float* out_sigma = out_rgb + (size_t)n * 3;

    int* ws = (int*)d_ws;
    int* counts = ws + WS_COUNTS;
    int* offsets = ws + WS_OFFSETS;
    int* cursor = ws + WS_CURSOR;
    int* order = ws + WS_ORDER;

    hipMemsetAsync(counts, 0, 4096 * sizeof(int), stream);
    hist_kernel<<<(n + 255) / 256, 256, 0, stream>>>(pts, counts, n);
    scan_kernel<<<1, 256, 0, stream>>>(counts, offsets, cursor);
    scatter_kernel<<<(n + 255) / 256, 256, 0, stream>>>(pts, cursor, order, n);
    expert_mlp_kernel<<<4096 * 2, 64, 0, stream>>>(
        pts, viewdirs, W1, b1, W2, b2, Wf, bfc, Wsig, bsig, Wv, bv, Wrgb, brgb,
        counts, offsets, order, out_rgb, out_sigma, samples);
}